// Round 1
// baseline (698.840 us; speedup 1.0000x reference)
//
#include <hip/hip_runtime.h>
#include <hip/hip_bf16.h>

#define N_NODES 131072
#define N_EDGES 524288
#define DHID    128
#define DIN     256

// ---------------- CSR build ----------------

__global__ __launch_bounds__(256) void count_edges(const int* __restrict__ dst,
                                                   int* __restrict__ counts) {
    int e = blockIdx.x * 256 + threadIdx.x;
    atomicAdd(&counts[dst[e]], 1);
}

__global__ __launch_bounds__(256) void scan1(const int* __restrict__ counts,
                                             int* __restrict__ offsets,
                                             int* __restrict__ bsums) {
    __shared__ int s[256];
    int i = blockIdx.x * 256 + threadIdx.x;
    int v = counts[i];
    s[threadIdx.x] = v;
    __syncthreads();
    for (int d = 1; d < 256; d <<= 1) {
        int t = (threadIdx.x >= d) ? s[threadIdx.x - d] : 0;
        __syncthreads();
        s[threadIdx.x] += t;
        __syncthreads();
    }
    offsets[i] = s[threadIdx.x] - v;                 // exclusive within block
    if (threadIdx.x == 255) bsums[blockIdx.x] = s[255];
}

__global__ __launch_bounds__(512) void scan2(int* __restrict__ bsums) {
    __shared__ int s[512];
    int v = bsums[threadIdx.x];
    s[threadIdx.x] = v;
    __syncthreads();
    for (int d = 1; d < 512; d <<= 1) {
        int t = (threadIdx.x >= d) ? s[threadIdx.x - d] : 0;
        __syncthreads();
        s[threadIdx.x] += t;
        __syncthreads();
    }
    bsums[threadIdx.x] = s[threadIdx.x] - v;         // exclusive
}

__global__ __launch_bounds__(256) void scan3(const int* __restrict__ counts,
                                             int* __restrict__ offsets,
                                             int* __restrict__ cursor,
                                             float* __restrict__ dinv,
                                             const int* __restrict__ bsums) {
    int i = blockIdx.x * 256 + threadIdx.x;
    int off = offsets[i] + bsums[blockIdx.x];        // blockIdx.x == i/256
    offsets[i] = off;
    cursor[i]  = off;
    dinv[i] = rsqrtf((float)(counts[i] + 1));        // +1 self-loop; deg>0 always
}

__global__ __launch_bounds__(256) void fill_csr(const int* __restrict__ src,
                                                const int* __restrict__ dst,
                                                int* __restrict__ cursor,
                                                int* __restrict__ csr_src) {
    int e = blockIdx.x * 256 + threadIdx.x;
    int d = dst[e];
    int p = atomicAdd(&cursor[d], 1);
    csr_src[p] = src[e];
}

// ---------------- GEMM: out[i][j] = sum_k A[row(i)][k]*W[j][k] + b[j] ----------------
// 32 nodes x 128 features per block, K tiled by 64, 4x4 register blocking.

template <int K, bool RELU, bool GATHER>
__global__ __launch_bounds__(256) void gemm_kernel(const float* __restrict__ A,
                                                   const int* __restrict__ tok,
                                                   const float* __restrict__ W,
                                                   const float* __restrict__ bias,
                                                   float* __restrict__ out) {
    constexpr int TN = 32;
    constexpr int KT = 64;
    __shared__ __align__(16) float Et[TN][KT];       // node rows, k-minor (8 KB)
    __shared__ __align__(16) float WtT[KT][132];     // k-major, +4 pad (33.8 KB)
    __shared__ int stok[TN];

    const int t = threadIdx.x;
    const int node0 = blockIdx.x * TN;
    const int jr = (t & 31) * 4;                     // feature base (0..124)
    const int ir = (t >> 5) * 4;                     // node base    (0..28)

    if (t < TN) stok[t] = GATHER ? tok[node0 + t] : (node0 + t);

    float4 acc[4];
    for (int n = 0; n < 4; ++n) acc[n] = make_float4(0.f, 0.f, 0.f, 0.f);

    for (int k0 = 0; k0 < K; k0 += KT) {
        __syncthreads();
        // stage A tile: 32 rows x 64 k — coalesced 256B per wave
#pragma unroll
        for (int r = 0; r < 8; ++r) {
            int idx = r * 256 + t;
            int i  = idx >> 6;
            int kk = idx & 63;
            Et[i][kk] = A[(size_t)stok[i] * K + k0 + kk];
        }
        // stage W tile transposed to k-major: coalesced global reads
#pragma unroll
        for (int r = 0; r < 32; ++r) {
            int idx = r * 256 + t;
            int j  = idx >> 6;
            int kk = idx & 63;
            WtT[kk][j] = W[j * K + k0 + kk];
        }
        __syncthreads();

#pragma unroll
        for (int kk = 0; kk < KT; kk += 4) {
            float4 a4[4];
#pragma unroll
            for (int n = 0; n < 4; ++n)
                a4[n] = *(const float4*)&Et[ir + n][kk];   // broadcast within half-wave
#pragma unroll
            for (int c = 0; c < 4; ++c) {
                float4 w = *(const float4*)&WtT[kk + c][jr]; // lanes -> consecutive 16B
#pragma unroll
                for (int n = 0; n < 4; ++n) {
                    float av = ((const float*)&a4[n])[c];
                    acc[n].x = fmaf(av, w.x, acc[n].x);
                    acc[n].y = fmaf(av, w.y, acc[n].y);
                    acc[n].z = fmaf(av, w.z, acc[n].z);
                    acc[n].w = fmaf(av, w.w, acc[n].w);
                }
            }
        }
    }

    float4 b4 = *(const float4*)&bias[jr];
#pragma unroll
    for (int n = 0; n < 4; ++n) {
        float4 v = acc[n];
        v.x += b4.x; v.y += b4.y; v.z += b4.z; v.w += b4.w;
        if (RELU) {
            v.x = fmaxf(v.x, 0.f); v.y = fmaxf(v.y, 0.f);
            v.z = fmaxf(v.z, 0.f); v.w = fmaxf(v.w, 0.f);
        }
        *(float4*)&out[(size_t)(node0 + ir + n) * DHID + jr] = v;
    }
}

// ---------------- aggregation: agg[i] = dinv[i]^2*x[i] + sum_e dinv[i]*dinv[s]*x[s] ----------------

__global__ __launch_bounds__(256) void aggregate_kernel(const float* __restrict__ x,
                                                        const int* __restrict__ csr_src,
                                                        const int* __restrict__ offsets,
                                                        const int* __restrict__ counts,
                                                        const float* __restrict__ dinv,
                                                        float* __restrict__ agg) {
    int node = blockIdx.x * 2 + (threadIdx.x >> 7);
    int f    = threadIdx.x & 127;
    float di = dinv[node];
    float acc = di * di * x[(size_t)node * DHID + f];   // self-loop
    int beg = offsets[node];
    int cnt = counts[node];
    for (int e = 0; e < cnt; ++e) {
        int s = csr_src[beg + e];
        acc = fmaf(di * dinv[s], x[(size_t)s * DHID + f], acc);
    }
    agg[(size_t)node * DHID + f] = acc;
}

// ---------------- metadata outputs ----------------

__global__ __launch_bounds__(256) void meta_kernel(const int* __restrict__ tok,
                                                   float* __restrict__ out) {
    int i = blockIdx.x * 256 + threadIdx.x;
    const size_t L0 = (size_t)N_NODES * DHID;           // 16777216
    out[L0 + i]               = (float)tok[i];          // labels
    out[L0 + N_NODES + i]     = 1.0f;                   // labels_mask (True)
    out[L0 + 2 * N_NODES + i] = (float)(i & 2047);      // label_node_ids (n=2048)
}

// ---------------- launch ----------------

extern "C" void kernel_launch(void* const* d_in, const int* in_sizes, int n_in,
                              void* d_out, int out_size, void* d_ws, size_t ws_size,
                              hipStream_t stream) {
    const int*   tok  = (const int*)d_in[0];
    const int*   esrc = (const int*)d_in[1];
    const int*   edst = esrc + N_EDGES;
    const float* emb  = (const float*)d_in[2];
    const float* Wn   = (const float*)d_in[3];
    const float* bn   = (const float*)d_in[4];
    const float* W1   = (const float*)d_in[5];
    const float* b1   = (const float*)d_in[6];
    const float* W2   = (const float*)d_in[7];
    const float* b2   = (const float*)d_in[8];
    float* out = (float*)d_out;

    char* ws = (char*)d_ws;
    int*   counts  = (int*)(ws);                    // 512 KB
    int*   offsets = (int*)(ws + (1u << 19));       // 512 KB
    int*   cursor  = (int*)(ws + (2u << 19));       // 512 KB
    float* dinv    = (float*)(ws + (3u << 19));     // 512 KB
    int*   bsums   = (int*)(ws + (4u << 19));       // 2 KB
    int*   csr     = (int*)(ws + (5u << 19));       // 2 MB (ends @4.5MB)
    float* agg     = (float*)(ws + (10u << 19));    // 64 MB @5MB offset

    hipMemsetAsync(counts, 0, N_NODES * sizeof(int), stream);
    count_edges<<<N_EDGES / 256, 256, 0, stream>>>(edst, counts);
    scan1<<<N_NODES / 256, 256, 0, stream>>>(counts, offsets, bsums);
    scan2<<<1, 512, 0, stream>>>(bsums);
    scan3<<<N_NODES / 256, 256, 0, stream>>>(counts, offsets, cursor, dinv, bsums);
    fill_csr<<<N_EDGES / 256, 256, 0, stream>>>(esrc, edst, cursor, csr);

    // x = embed[tok] @ Wn^T + bn   -> d_out[0:N*128] (used as scratch X/H buffer)
    gemm_kernel<DIN, false, true><<<N_NODES / 32, 256, 0, stream>>>(emb, tok, Wn, bn, out);
    // conv1: aggregate-then-linear (commutes), relu fused in epilogue
    aggregate_kernel<<<N_NODES / 2, 256, 0, stream>>>(out, csr, offsets, counts, dinv, agg);
    gemm_kernel<DHID, true, false><<<N_NODES / 32, 256, 0, stream>>>(agg, nullptr, W1, b1, out);
    // conv2
    aggregate_kernel<<<N_NODES / 2, 256, 0, stream>>>(out, csr, offsets, counts, dinv, agg);
    gemm_kernel<DHID, false, false><<<N_NODES / 32, 256, 0, stream>>>(agg, nullptr, W2, b2, out);

    meta_kernel<<<N_NODES / 256, 256, 0, stream>>>(tok, out);
}

// Round 2
// 406.769 us; speedup vs baseline: 1.7180x; 1.7180x over previous
//
#include <hip/hip_runtime.h>
#include <hip/hip_bf16.h>

#define N_NODES 131072
#define N_EDGES 524288
#define DHID    128
#define DIN     256

typedef __attribute__((ext_vector_type(8))) short short8;
typedef __attribute__((ext_vector_type(4))) float floatx4;

__device__ inline short bf16_rne(float f) {
    union { float f; unsigned u; } v; v.f = f;
    unsigned r = v.u + 0x7FFF + ((v.u >> 16) & 1);
    return (short)(r >> 16);
}

// ---------------- CSR build ----------------

__global__ __launch_bounds__(256) void count_edges(const int* __restrict__ dst,
                                                   int* __restrict__ counts) {
    int e = blockIdx.x * 256 + threadIdx.x;
    atomicAdd(&counts[dst[e]], 1);
}

__global__ __launch_bounds__(256) void scan1(const int* __restrict__ counts,
                                             int* __restrict__ offsets,
                                             int* __restrict__ bsums) {
    __shared__ int s[256];
    int i = blockIdx.x * 256 + threadIdx.x;
    int v = counts[i];
    s[threadIdx.x] = v;
    __syncthreads();
    for (int d = 1; d < 256; d <<= 1) {
        int t = (threadIdx.x >= d) ? s[threadIdx.x - d] : 0;
        __syncthreads();
        s[threadIdx.x] += t;
        __syncthreads();
    }
    offsets[i] = s[threadIdx.x] - v;                 // exclusive within block
    if (threadIdx.x == 255) bsums[blockIdx.x] = s[255];
}

__global__ __launch_bounds__(512) void scan2(int* __restrict__ bsums) {
    __shared__ int s[512];
    int v = bsums[threadIdx.x];
    s[threadIdx.x] = v;
    __syncthreads();
    for (int d = 1; d < 512; d <<= 1) {
        int t = (threadIdx.x >= d) ? s[threadIdx.x - d] : 0;
        __syncthreads();
        s[threadIdx.x] += t;
        __syncthreads();
    }
    bsums[threadIdx.x] = s[threadIdx.x] - v;         // exclusive
}

__global__ __launch_bounds__(256) void scan3(const int* __restrict__ counts,
                                             int* __restrict__ offsets,
                                             int* __restrict__ cursor,
                                             float* __restrict__ dinv,
                                             const int* __restrict__ bsums) {
    int i = blockIdx.x * 256 + threadIdx.x;
    int off = offsets[i] + bsums[blockIdx.x];        // blockIdx.x == i/256
    offsets[i] = off;
    cursor[i]  = off;
    dinv[i] = rsqrtf((float)(counts[i] + 1));        // +1 self-loop; deg>0 always
}

__global__ __launch_bounds__(256) void fill_csr(const int* __restrict__ src,
                                                const int* __restrict__ dst,
                                                int* __restrict__ cursor,
                                                int* __restrict__ csr_src) {
    int e = blockIdx.x * 256 + threadIdx.x;
    int d = dst[e];
    int p = atomicAdd(&cursor[d], 1);
    csr_src[p] = src[e];
}

// ---------------- MFMA GEMM: out[i][j] = sum_k A[row(i)][k]*W[j][k] + b[j] ----------------
// 128 nodes x 128 features per block; 4 waves, each 32 nodes x 128 feats
// = 2x8 tiles of 16x16, K chunked by 64, fp32->bf16 conversion in staging.

template <int K, bool RELU, bool GATHER>
__global__ __launch_bounds__(256) void gemm_mfma(const float* __restrict__ A,
                                                 const int* __restrict__ tok,
                                                 const float* __restrict__ W,
                                                 const float* __restrict__ bias,
                                                 float* __restrict__ out) {
    constexpr int TM = 128;
    constexpr int KT = 64;
    constexpr int RS = 72;                     // bf16 row stride: 144 B -> 2-way bank alias (free)
    __shared__ short As[TM * RS];              // 18.0 KB
    __shared__ short Ws_[DHID * RS];           // 18.0 KB
    __shared__ int stok[TM];

    const int t = threadIdx.x;
    const int node0 = blockIdx.x * TM;
    const int wid  = t >> 6;
    const int lane = t & 63;
    const int col  = lane & 15;
    const int quad = lane >> 4;

    if (GATHER && t < TM) stok[t] = tok[node0 + t];

    floatx4 acc[2][8] = {};

    float bv[8];
#pragma unroll
    for (int ft = 0; ft < 8; ++ft) bv[ft] = bias[ft * 16 + col];

    for (int k0 = 0; k0 < K; k0 += KT) {
        __syncthreads();                       // also covers stok visibility (1st iter)
        // stage A tile: 128 rows x 64 k, float4 loads, bf16 packed 8B LDS writes
#pragma unroll
        for (int i = 0; i < 8; ++i) {
            int q   = i * 256 + t;             // float4 id in tile
            int row = q >> 4;
            int k4  = (q & 15) * 4;
            size_t arow = GATHER ? (size_t)stok[row] : (size_t)(node0 + row);
            float4 v = *(const float4*)&A[arow * K + k0 + k4];
            union { short s[4]; unsigned long long u; } pk;
            pk.s[0] = bf16_rne(v.x); pk.s[1] = bf16_rne(v.y);
            pk.s[2] = bf16_rne(v.z); pk.s[3] = bf16_rne(v.w);
            *(unsigned long long*)&As[row * RS + k4] = pk.u;
        }
        // stage W tile: 128 feature rows x 64 k
#pragma unroll
        for (int i = 0; i < 8; ++i) {
            int q   = i * 256 + t;
            int row = q >> 4;
            int k4  = (q & 15) * 4;
            float4 v = *(const float4*)&W[row * K + k0 + k4];
            union { short s[4]; unsigned long long u; } pk;
            pk.s[0] = bf16_rne(v.x); pk.s[1] = bf16_rne(v.y);
            pk.s[2] = bf16_rne(v.z); pk.s[3] = bf16_rne(v.w);
            *(unsigned long long*)&Ws_[row * RS + k4] = pk.u;
        }
        __syncthreads();

#pragma unroll
        for (int s = 0; s < 2; ++s) {
            int kk = s * 32 + quad * 8;
            short8 a0 = *(const short8*)&As[(wid * 32 +      col) * RS + kk];
            short8 a1 = *(const short8*)&As[(wid * 32 + 16 + col) * RS + kk];
#pragma unroll
            for (int ft = 0; ft < 8; ++ft) {
                short8 b = *(const short8*)&Ws_[(ft * 16 + col) * RS + kk];
                acc[0][ft] = __builtin_amdgcn_mfma_f32_16x16x32_bf16(a0, b, acc[0][ft], 0, 0, 0);
                acc[1][ft] = __builtin_amdgcn_mfma_f32_16x16x32_bf16(a1, b, acc[1][ft], 0, 0, 0);
            }
        }
    }

    // epilogue: C/D layout col=lane&15, row=quad*4+reg
#pragma unroll
    for (int mt = 0; mt < 2; ++mt) {
        int mbase = node0 + wid * 32 + mt * 16 + quad * 4;
#pragma unroll
        for (int ft = 0; ft < 8; ++ft) {
#pragma unroll
            for (int r = 0; r < 4; ++r) {
                float v = acc[mt][ft][r] + bv[ft];
                if (RELU) v = fmaxf(v, 0.f);
                out[(size_t)(mbase + r) * DHID + ft * 16 + col] = v;
            }
        }
    }
}

// ---------------- aggregation: agg[i] = dinv[i]^2*x[i] + sum_e dinv[i]*dinv[s]*x[s] ----------------
// 32 threads per node (float4 per lane), 8 nodes per block.

__global__ __launch_bounds__(256) void aggregate_kernel(const float* __restrict__ x,
                                                        const int* __restrict__ csr_src,
                                                        const int* __restrict__ offsets,
                                                        const int* __restrict__ counts,
                                                        const float* __restrict__ dinv,
                                                        float* __restrict__ agg) {
    int node = blockIdx.x * 8 + (threadIdx.x >> 5);
    int f4   = (threadIdx.x & 31) * 4;
    float di = dinv[node];
    float4 xv = *(const float4*)&x[(size_t)node * DHID + f4];
    float s2 = di * di;
    float4 acc = make_float4(s2 * xv.x, s2 * xv.y, s2 * xv.z, s2 * xv.w);
    int beg = offsets[node];
    int cnt = counts[node];
    for (int e = 0; e < cnt; ++e) {
        int s = csr_src[beg + e];
        float w = di * dinv[s];
        float4 v = *(const float4*)&x[(size_t)s * DHID + f4];
        acc.x = fmaf(w, v.x, acc.x);
        acc.y = fmaf(w, v.y, acc.y);
        acc.z = fmaf(w, v.z, acc.z);
        acc.w = fmaf(w, v.w, acc.w);
    }
    *(float4*)&agg[(size_t)node * DHID + f4] = acc;
}

// ---------------- metadata outputs ----------------

__global__ __launch_bounds__(256) void meta_kernel(const int* __restrict__ tok,
                                                   float* __restrict__ out) {
    int i = blockIdx.x * 256 + threadIdx.x;
    const size_t L0 = (size_t)N_NODES * DHID;           // 16777216
    out[L0 + i]               = (float)tok[i];          // labels
    out[L0 + N_NODES + i]     = 1.0f;                   // labels_mask (True)
    out[L0 + 2 * N_NODES + i] = (float)(i & 2047);      // label_node_ids (n=2048)
}

// ---------------- launch ----------------

extern "C" void kernel_launch(void* const* d_in, const int* in_sizes, int n_in,
                              void* d_out, int out_size, void* d_ws, size_t ws_size,
                              hipStream_t stream) {
    const int*   tok  = (const int*)d_in[0];
    const int*   esrc = (const int*)d_in[1];
    const int*   edst = esrc + N_EDGES;
    const float* emb  = (const float*)d_in[2];
    const float* Wn   = (const float*)d_in[3];
    const float* bn   = (const float*)d_in[4];
    const float* W1   = (const float*)d_in[5];
    const float* b1   = (const float*)d_in[6];
    const float* W2   = (const float*)d_in[7];
    const float* b2   = (const float*)d_in[8];
    float* out = (float*)d_out;

    char* ws = (char*)d_ws;
    int*   counts  = (int*)(ws);                    // 512 KB
    int*   offsets = (int*)(ws + (1u << 19));       // 512 KB
    int*   cursor  = (int*)(ws + (2u << 19));       // 512 KB
    float* dinv    = (float*)(ws + (3u << 19));     // 512 KB
    int*   bsums   = (int*)(ws + (4u << 19));       // 2 KB
    int*   csr     = (int*)(ws + (5u << 19));       // 2 MB (ends @4.5MB)
    float* agg     = (float*)(ws + (10u << 19));    // 64 MB @5MB offset

    hipMemsetAsync(counts, 0, N_NODES * sizeof(int), stream);
    count_edges<<<N_EDGES / 256, 256, 0, stream>>>(edst, counts);
    scan1<<<N_NODES / 256, 256, 0, stream>>>(counts, offsets, bsums);
    scan2<<<1, 512, 0, stream>>>(bsums);
    scan3<<<N_NODES / 256, 256, 0, stream>>>(counts, offsets, cursor, dinv, bsums);
    fill_csr<<<N_EDGES / 256, 256, 0, stream>>>(esrc, edst, cursor, csr);

    // x = embed[tok] @ Wn^T + bn   -> d_out[0:N*128] (used as scratch X/H buffer)
    gemm_mfma<DIN, false, true><<<N_NODES / 128, 256, 0, stream>>>(emb, tok, Wn, bn, out);
    // conv1: aggregate-then-linear (commutes), relu fused in gemm epilogue
    aggregate_kernel<<<N_NODES / 8, 256, 0, stream>>>(out, csr, offsets, counts, dinv, agg);
    gemm_mfma<DHID, true, false><<<N_NODES / 128, 256, 0, stream>>>(agg, nullptr, W1, b1, out);
    // conv2
    aggregate_kernel<<<N_NODES / 8, 256, 0, stream>>>(out, csr, offsets, counts, dinv, agg);
    gemm_mfma<DHID, false, false><<<N_NODES / 128, 256, 0, stream>>>(agg, nullptr, W2, b2, out);

    meta_kernel<<<N_NODES / 256, 256, 0, stream>>>(tok, out);
}

// Round 3
// 361.508 us; speedup vs baseline: 1.9331x; 1.1252x over previous
//
#include <hip/hip_runtime.h>
#include <hip/hip_bf16.h>

#define N_NODES 131072
#define N_EDGES 524288
#define DHID    128
#define DIN     256

typedef __attribute__((ext_vector_type(8))) short short8;
typedef __attribute__((ext_vector_type(4))) float floatx4;

__device__ inline short bf16_rne(float f) {
    union { float f; unsigned u; } v; v.f = f;
    unsigned r = v.u + 0x7FFF + ((v.u >> 16) & 1);
    return (short)(r >> 16);
}
__device__ inline float bf16_to_f(short s) {
    union { unsigned u; float f; } v; v.u = ((unsigned)(unsigned short)s) << 16;
    return v.f;
}

// ---------------- CSR build ----------------

__global__ __launch_bounds__(256) void count_edges(const int* __restrict__ dst,
                                                   int* __restrict__ counts) {
    int e = blockIdx.x * 256 + threadIdx.x;
    atomicAdd(&counts[dst[e]], 1);
}

__global__ __launch_bounds__(256) void scan1(const int* __restrict__ counts,
                                             int* __restrict__ offsets,
                                             int* __restrict__ bsums) {
    __shared__ int s[256];
    int i = blockIdx.x * 256 + threadIdx.x;
    int v = counts[i];
    s[threadIdx.x] = v;
    __syncthreads();
    for (int d = 1; d < 256; d <<= 1) {
        int t = (threadIdx.x >= d) ? s[threadIdx.x - d] : 0;
        __syncthreads();
        s[threadIdx.x] += t;
        __syncthreads();
    }
    offsets[i] = s[threadIdx.x] - v;
    if (threadIdx.x == 255) bsums[blockIdx.x] = s[255];
}

__global__ __launch_bounds__(512) void scan2(int* __restrict__ bsums) {
    __shared__ int s[512];
    int v = bsums[threadIdx.x];
    s[threadIdx.x] = v;
    __syncthreads();
    for (int d = 1; d < 512; d <<= 1) {
        int t = (threadIdx.x >= d) ? s[threadIdx.x - d] : 0;
        __syncthreads();
        s[threadIdx.x] += t;
        __syncthreads();
    }
    bsums[threadIdx.x] = s[threadIdx.x] - v;
}

__global__ __launch_bounds__(256) void scan3(const int* __restrict__ counts,
                                             int* __restrict__ offsets,
                                             int* __restrict__ cursor,
                                             float* __restrict__ dinv,
                                             const int* __restrict__ bsums) {
    int i = blockIdx.x * 256 + threadIdx.x;
    int off = offsets[i] + bsums[blockIdx.x];
    offsets[i] = off;
    cursor[i]  = off;
    dinv[i] = rsqrtf((float)(counts[i] + 1));
}

__global__ __launch_bounds__(256) void fill_csr(const int* __restrict__ src,
                                                const int* __restrict__ dst,
                                                int* __restrict__ cursor,
                                                int* __restrict__ csr_src) {
    int e = blockIdx.x * 256 + threadIdx.x;
    int d = dst[e];
    int p = atomicAdd(&cursor[d], 1);
    csr_src[p] = src[e];
}

// ---------------- weight fp32 -> bf16 conversion (once per call) ----------------

__global__ __launch_bounds__(256) void convert_weights(const float* __restrict__ Wn,
                                                       const float* __restrict__ W1,
                                                       const float* __restrict__ W2,
                                                       short* __restrict__ Wnb,
                                                       short* __restrict__ W1b,
                                                       short* __restrict__ W2b) {
    int i = blockIdx.x * 256 + threadIdx.x;          // 65536 total
    if (i < 32768)      Wnb[i] = bf16_rne(Wn[i]);
    else if (i < 49152) W1b[i - 32768] = bf16_rne(W1[i - 32768]);
    else                W2b[i - 49152] = bf16_rne(W2[i - 49152]);
}

// ---------------- zero-LDS MFMA GEMM ----------------
// out[i][j] = sum_k A[row(i)][k] * W[j][k] + b[j]
// 4 waves/block, each wave: 32 nodes x 128 feats = 2x8 tiles of 16x16x32.
// A-frags and B-frags loaded straight from global (B is L1/L2-hot: whole W
// is 32-64KB shared by every wave). No LDS, no barriers.

template <int K, bool RELU, bool GATHER, bool OUT_BF16>
__global__ __launch_bounds__(256) void gemm_mfma(const void* __restrict__ Aptr,
                                                 const int* __restrict__ tok,
                                                 const short* __restrict__ Wb,
                                                 const float* __restrict__ bias,
                                                 void* __restrict__ outp) {
    const int t = threadIdx.x;
    const int wid  = t >> 6;
    const int lane = t & 63;
    const int col  = lane & 15;
    const int quad = lane >> 4;
    const int base = blockIdx.x * 128 + wid * 32;

    const short* Ab = (const short*)Aptr;
    const float* Af = (const float*)Aptr;

    size_t row0, row1;
    if (GATHER) {
        row0 = (size_t)tok[base + col];
        row1 = (size_t)tok[base + 16 + col];
    } else {
        row0 = (size_t)(base + col);
        row1 = (size_t)(base + 16 + col);
    }

    floatx4 acc[2][8] = {};

#pragma unroll 4
    for (int kc = 0; kc < K / 32; ++kc) {
        const int ko = kc * 32 + quad * 8;
        short8 a0, a1;
        if (GATHER) {
            float4 v0 = *(const float4*)&Af[row0 * K + ko];
            float4 v1 = *(const float4*)&Af[row0 * K + ko + 4];
            float4 u0 = *(const float4*)&Af[row1 * K + ko];
            float4 u1 = *(const float4*)&Af[row1 * K + ko + 4];
            a0[0] = bf16_rne(v0.x); a0[1] = bf16_rne(v0.y);
            a0[2] = bf16_rne(v0.z); a0[3] = bf16_rne(v0.w);
            a0[4] = bf16_rne(v1.x); a0[5] = bf16_rne(v1.y);
            a0[6] = bf16_rne(v1.z); a0[7] = bf16_rne(v1.w);
            a1[0] = bf16_rne(u0.x); a1[1] = bf16_rne(u0.y);
            a1[2] = bf16_rne(u0.z); a1[3] = bf16_rne(u0.w);
            a1[4] = bf16_rne(u1.x); a1[5] = bf16_rne(u1.y);
            a1[6] = bf16_rne(u1.z); a1[7] = bf16_rne(u1.w);
        } else {
            a0 = *(const short8*)&Ab[row0 * K + ko];
            a1 = *(const short8*)&Ab[row1 * K + ko];
        }
#pragma unroll
        for (int ft = 0; ft < 8; ++ft) {
            short8 b = *(const short8*)&Wb[(size_t)(ft * 16 + col) * K + ko];
            acc[0][ft] = __builtin_amdgcn_mfma_f32_16x16x32_bf16(a0, b, acc[0][ft], 0, 0, 0);
            acc[1][ft] = __builtin_amdgcn_mfma_f32_16x16x32_bf16(a1, b, acc[1][ft], 0, 0, 0);
        }
    }

    // epilogue: C/D layout col=lane&15, row=quad*4+reg
    short* outb = (short*)outp;
    float* outf = (float*)outp;
#pragma unroll
    for (int ft = 0; ft < 8; ++ft) {
        float bv = bias[ft * 16 + col];
#pragma unroll
        for (int mt = 0; mt < 2; ++mt) {
            int mbase = base + mt * 16 + quad * 4;
#pragma unroll
            for (int r = 0; r < 4; ++r) {
                float v = acc[mt][ft][r] + bv;
                if (RELU) v = fmaxf(v, 0.f);
                size_t idx = (size_t)(mbase + r) * DHID + ft * 16 + col;
                if (OUT_BF16) outb[idx] = bf16_rne(v);
                else          outf[idx] = v;
            }
        }
    }
}

// ---------------- aggregation (bf16 in/out, fp32 accumulate) ----------------
// agg[i] = dinv[i]^2*x[i] + sum_e dinv[i]*dinv[src]*x[src]; 16 lanes per node.

__global__ __launch_bounds__(256) void aggregate_kernel(const short* __restrict__ x,
                                                        const int* __restrict__ csr_src,
                                                        const int* __restrict__ offsets,
                                                        const int* __restrict__ counts,
                                                        const float* __restrict__ dinv,
                                                        short* __restrict__ agg) {
    int node = blockIdx.x * 16 + (threadIdx.x >> 4);
    int f8   = (threadIdx.x & 15) * 8;
    float di = dinv[node];
    float s2 = di * di;
    short8 xv = *(const short8*)&x[(size_t)node * DHID + f8];
    float acc[8];
#pragma unroll
    for (int j = 0; j < 8; ++j) acc[j] = s2 * bf16_to_f(xv[j]);

    int beg = offsets[node];
    int cnt = counts[node];
    for (int e = 0; e < cnt; ++e) {
        int s = csr_src[beg + e];
        float w = di * dinv[s];
        short8 v = *(const short8*)&x[(size_t)s * DHID + f8];
#pragma unroll
        for (int j = 0; j < 8; ++j) acc[j] = fmaf(w, bf16_to_f(v[j]), acc[j]);
    }
    short8 o;
#pragma unroll
    for (int j = 0; j < 8; ++j) o[j] = bf16_rne(acc[j]);
    *(short8*)&agg[(size_t)node * DHID + f8] = o;
}

// ---------------- metadata outputs ----------------

__global__ __launch_bounds__(256) void meta_kernel(const int* __restrict__ tok,
                                                   float* __restrict__ out) {
    int i = blockIdx.x * 256 + threadIdx.x;
    const size_t L0 = (size_t)N_NODES * DHID;
    out[L0 + i]               = (float)tok[i];
    out[L0 + N_NODES + i]     = 1.0f;
    out[L0 + 2 * N_NODES + i] = (float)(i & 2047);
}

// ---------------- launch ----------------

extern "C" void kernel_launch(void* const* d_in, const int* in_sizes, int n_in,
                              void* d_out, int out_size, void* d_ws, size_t ws_size,
                              hipStream_t stream) {
    const int*   tok  = (const int*)d_in[0];
    const int*   esrc = (const int*)d_in[1];
    const int*   edst = esrc + N_EDGES;
    const float* emb  = (const float*)d_in[2];
    const float* Wn   = (const float*)d_in[3];
    const float* bn   = (const float*)d_in[4];
    const float* W1   = (const float*)d_in[5];
    const float* b1   = (const float*)d_in[6];
    const float* W2   = (const float*)d_in[7];
    const float* b2   = (const float*)d_in[8];
    float* out = (float*)d_out;

    char* ws = (char*)d_ws;
    int*   counts  = (int*)(ws);                      // 512 KB
    int*   offsets = (int*)(ws + (1u << 19));         // 512 KB
    int*   cursor  = (int*)(ws + (2u << 19));         // 512 KB
    float* dinv    = (float*)(ws + (3u << 19));       // 512 KB
    int*   bsums   = (int*)(ws + (4u << 19));         // 2 KB (64 KB slot)
    int*   csr     = (int*)(ws + 3 * (1u << 20));     // 2 MB @3MB
    short* Wnb     = (short*)(ws + 5 * (1u << 20));   // 64 KB @5MB
    short* W1b     = (short*)(ws + 5 * (1u << 20) + (1u << 18)); // 32 KB
    short* W2b     = (short*)(ws + 5 * (1u << 20) + (2u << 18)); // 32 KB
    short* aggb    = (short*)(ws + 6 * (1u << 20));   // 33.5 MB @6MB
    short* xb      = (short*)d_out;                   // 33.5 MB scratch in d_out
                                                      // (overwritten by final fp32 write)

    hipMemsetAsync(counts, 0, N_NODES * sizeof(int), stream);
    count_edges<<<N_EDGES / 256, 256, 0, stream>>>(edst, counts);
    scan1<<<N_NODES / 256, 256, 0, stream>>>(counts, offsets, bsums);
    scan2<<<1, 512, 0, stream>>>(bsums);
    scan3<<<N_NODES / 256, 256, 0, stream>>>(counts, offsets, cursor, dinv, bsums);
    fill_csr<<<N_EDGES / 256, 256, 0, stream>>>(esrc, edst, cursor, csr);
    convert_weights<<<65536 / 256, 256, 0, stream>>>(Wn, W1, W2, Wnb, W1b, W2b);

    // x = bf16(embed[tok] @ Wn^T + bn) -> xb (d_out scratch)
    gemm_mfma<DIN, false, true, true><<<N_NODES / 128, 256, 0, stream>>>(emb, tok, Wnb, bn, xb);
    // conv1 (aggregate-then-linear commutes; relu in epilogue)
    aggregate_kernel<<<N_NODES / 16, 256, 0, stream>>>(xb, csr, offsets, counts, dinv, aggb);
    gemm_mfma<DHID, true, false, true><<<N_NODES / 128, 256, 0, stream>>>(aggb, nullptr, W1b, b1, xb);
    // conv2: final GEMM writes fp32 straight to d_out
    aggregate_kernel<<<N_NODES / 16, 256, 0, stream>>>(xb, csr, offsets, counts, dinv, aggb);
    gemm_mfma<DHID, false, false, false><<<N_NODES / 128, 256, 0, stream>>>(aggb, nullptr, W2b, b2, out);

    meta_kernel<<<N_NODES / 256, 256, 0, stream>>>(tok, out);
}

// Round 4
// 352.443 us; speedup vs baseline: 1.9828x; 1.0257x over previous
//
#include <hip/hip_runtime.h>
#include <hip/hip_bf16.h>

#define N_NODES 131072
#define N_EDGES 524288
#define DHID    128
#define DIN     256

typedef __attribute__((ext_vector_type(8))) short short8;
typedef __attribute__((ext_vector_type(4))) float floatx4;

__device__ inline short bf16_rne(float f) {
    union { float f; unsigned u; } v; v.f = f;
    unsigned r = v.u + 0x7FFF + ((v.u >> 16) & 1);
    return (short)(r >> 16);
}
__device__ inline float bf16_to_f(short s) {
    union { unsigned u; float f; } v; v.u = ((unsigned)(unsigned short)s) << 16;
    return v.f;
}

// ---------------- CSR build ----------------

__global__ __launch_bounds__(256) void count_edges(const int* __restrict__ dst,
                                                   int* __restrict__ counts) {
    int e = blockIdx.x * 256 + threadIdx.x;
    atomicAdd(&counts[dst[e]], 1);
}

__global__ __launch_bounds__(256) void scan1(const int* __restrict__ counts,
                                             int* __restrict__ offsets,
                                             int* __restrict__ bsums) {
    __shared__ int s[256];
    int i = blockIdx.x * 256 + threadIdx.x;
    int v = counts[i];
    s[threadIdx.x] = v;
    __syncthreads();
    for (int d = 1; d < 256; d <<= 1) {
        int t = (threadIdx.x >= d) ? s[threadIdx.x - d] : 0;
        __syncthreads();
        s[threadIdx.x] += t;
        __syncthreads();
    }
    offsets[i] = s[threadIdx.x] - v;
    if (threadIdx.x == 255) bsums[blockIdx.x] = s[255];
}

__global__ __launch_bounds__(512) void scan2(int* __restrict__ bsums) {
    __shared__ int s[512];
    int v = bsums[threadIdx.x];
    s[threadIdx.x] = v;
    __syncthreads();
    for (int d = 1; d < 512; d <<= 1) {
        int t = (threadIdx.x >= d) ? s[threadIdx.x - d] : 0;
        __syncthreads();
        s[threadIdx.x] += t;
        __syncthreads();
    }
    bsums[threadIdx.x] = s[threadIdx.x] - v;
}

__global__ __launch_bounds__(256) void scan3(const int* __restrict__ counts,
                                             int* __restrict__ offsets,
                                             int* __restrict__ cursor,
                                             float* __restrict__ dinv,
                                             const int* __restrict__ bsums) {
    int i = blockIdx.x * 256 + threadIdx.x;
    int off = offsets[i] + bsums[blockIdx.x];
    offsets[i] = off;
    cursor[i]  = off;
    dinv[i] = rsqrtf((float)(counts[i] + 1));
}

__global__ __launch_bounds__(256) void fill_csr(const int* __restrict__ src,
                                                const int* __restrict__ dst,
                                                int* __restrict__ cursor,
                                                int* __restrict__ csr_src) {
    int e = blockIdx.x * 256 + threadIdx.x;
    int d = dst[e];
    int p = atomicAdd(&cursor[d], 1);
    csr_src[p] = src[e];
}

// ---------------- fp32 -> bf16 conversions (once per call) ----------------

__global__ __launch_bounds__(256) void convert_weights(const float* __restrict__ Wn,
                                                       const float* __restrict__ W1,
                                                       const float* __restrict__ W2,
                                                       short* __restrict__ Wnb,
                                                       short* __restrict__ W1b,
                                                       short* __restrict__ W2b) {
    int i = blockIdx.x * 256 + threadIdx.x;          // 65536 total
    if (i < 32768)      Wnb[i] = bf16_rne(Wn[i]);
    else if (i < 49152) W1b[i - 32768] = bf16_rne(W1[i - 32768]);
    else                W2b[i - 49152] = bf16_rne(W2[i - 49152]);
}

__global__ __launch_bounds__(256) void convert_emb(const float* __restrict__ in,
                                                   short* __restrict__ outb) {
    size_t i = (size_t)(blockIdx.x * 256 + threadIdx.x) * 8;   // 32000*256 = 8192000
    float4 v0 = *(const float4*)&in[i];
    float4 v1 = *(const float4*)&in[i + 4];
    short8 o;
    o[0] = bf16_rne(v0.x); o[1] = bf16_rne(v0.y);
    o[2] = bf16_rne(v0.z); o[3] = bf16_rne(v0.w);
    o[4] = bf16_rne(v1.x); o[5] = bf16_rne(v1.y);
    o[6] = bf16_rne(v1.z); o[7] = bf16_rne(v1.w);
    *(short8*)&outb[i] = o;
}

// ---------------- embed GEMM: out[i][:] = embb[tok[i]] @ Wn^T + bn ----------------
// Zero-LDS, zero-barrier. 4 waves/block, 32 nodes/wave, K=256, all-bf16 loads.

__global__ __launch_bounds__(256) void gemm_embed(const short* __restrict__ Ab,
                                                  const int* __restrict__ tok,
                                                  const short* __restrict__ Wb,
                                                  const float* __restrict__ bias,
                                                  short* __restrict__ out) {
    const int t = threadIdx.x;
    const int wid  = t >> 6;
    const int lane = t & 63;
    const int col  = lane & 15;
    const int quad = lane >> 4;
    const int base = blockIdx.x * 128 + wid * 32;

    const size_t row0 = (size_t)tok[base + col];
    const size_t row1 = (size_t)tok[base + 16 + col];

    floatx4 acc[2][8] = {};

#pragma unroll
    for (int kc = 0; kc < DIN / 32; ++kc) {
        const int ko = kc * 32 + quad * 8;
        short8 a0 = *(const short8*)&Ab[row0 * DIN + ko];
        short8 a1 = *(const short8*)&Ab[row1 * DIN + ko];
#pragma unroll
        for (int ft = 0; ft < 8; ++ft) {
            short8 b = *(const short8*)&Wb[(size_t)(ft * 16 + col) * DIN + ko];
            acc[0][ft] = __builtin_amdgcn_mfma_f32_16x16x32_bf16(a0, b, acc[0][ft], 0, 0, 0);
            acc[1][ft] = __builtin_amdgcn_mfma_f32_16x16x32_bf16(a1, b, acc[1][ft], 0, 0, 0);
        }
    }

#pragma unroll
    for (int ft = 0; ft < 8; ++ft) {
        float bv = bias[ft * 16 + col];
#pragma unroll
        for (int mt = 0; mt < 2; ++mt) {
            int mbase = base + mt * 16 + quad * 4;
#pragma unroll
            for (int r = 0; r < 4; ++r) {
                float v = acc[mt][ft][r] + bv;
                out[(size_t)(mbase + r) * DHID + ft * 16 + col] = bf16_rne(v);
            }
        }
    }
}

// ---------------- fused GCN conv: out = act((dinv^2*x + gather-sum) @ W^T + b) ----------------
// One wave = 16 nodes. Lane (col=lane&15, quad=lane>>4) aggregates node base+col,
// feature slices {quad*8 + 32c}, in fp32 regs — which IS the MFMA A-fragment
// layout (A[m=lane&15][k=quad*8+j]). Then 32 MFMAs with W. No LDS, no barriers,
// no agg round-trip.

template <bool RELU, bool OUT_BF16>
__global__ __launch_bounds__(256) void fused_conv(const short* __restrict__ x,
                                                  const int* __restrict__ csr_src,
                                                  const int* __restrict__ offsets,
                                                  const int* __restrict__ counts,
                                                  const float* __restrict__ dinv,
                                                  const short* __restrict__ Wb,
                                                  const float* __restrict__ bias,
                                                  void* __restrict__ outp) {
    const int t = threadIdx.x;
    const int wid  = t >> 6;
    const int lane = t & 63;
    const int col  = lane & 15;
    const int quad = lane >> 4;
    const int base = (blockIdx.x * 4 + wid) * 16;
    const int node = base + col;

    const float di = dinv[node];
    const float s2 = di * di;
    const int beg = offsets[node];
    const int cnt = counts[node];

    // self-loop init
    float af[4][8];
    {
        const size_t xrow = (size_t)node * DHID + quad * 8;
#pragma unroll
        for (int c = 0; c < 4; ++c) {
            short8 v = *(const short8*)&x[xrow + c * 32];
#pragma unroll
            for (int j = 0; j < 8; ++j) af[c][j] = s2 * bf16_to_f(v[j]);
        }
    }

    // edge loop: gather src rows, fp32 accumulate; prefetch next index
    int s_next = (cnt > 0) ? csr_src[beg] : 0;
    for (int e = 0; e < cnt; ++e) {
        int s = s_next;
        s_next = (e + 1 < cnt) ? csr_src[beg + e + 1] : 0;
        float w = di * dinv[s];
        const size_t srow = (size_t)s * DHID + quad * 8;
        short8 v0 = *(const short8*)&x[srow];
        short8 v1 = *(const short8*)&x[srow + 32];
        short8 v2 = *(const short8*)&x[srow + 64];
        short8 v3 = *(const short8*)&x[srow + 96];
#pragma unroll
        for (int j = 0; j < 8; ++j) {
            af[0][j] = fmaf(w, bf16_to_f(v0[j]), af[0][j]);
            af[1][j] = fmaf(w, bf16_to_f(v1[j]), af[1][j]);
            af[2][j] = fmaf(w, bf16_to_f(v2[j]), af[2][j]);
            af[3][j] = fmaf(w, bf16_to_f(v3[j]), af[3][j]);
        }
    }

    // round aggregated A-fragments to bf16
    short8 a[4];
#pragma unroll
    for (int c = 0; c < 4; ++c)
#pragma unroll
        for (int j = 0; j < 8; ++j) a[c][j] = bf16_rne(af[c][j]);

    // MFMA with weights (L1-hot: same 32KB W for every wave)
    floatx4 acc[8] = {};
#pragma unroll
    for (int c = 0; c < 4; ++c) {
        const int ko = c * 32 + quad * 8;
#pragma unroll
        for (int ft = 0; ft < 8; ++ft) {
            short8 b = *(const short8*)&Wb[(size_t)(ft * 16 + col) * DHID + ko];
            acc[ft] = __builtin_amdgcn_mfma_f32_16x16x32_bf16(a[c], b, acc[ft], 0, 0, 0);
        }
    }

    // epilogue: D layout col=lane&15 (feature), row=quad*4+reg (node)
    short* outb = (short*)outp;
    float* outf = (float*)outp;
#pragma unroll
    for (int ft = 0; ft < 8; ++ft) {
        float bv = bias[ft * 16 + col];
#pragma unroll
        for (int r = 0; r < 4; ++r) {
            float v = acc[ft][r] + bv;
            if (RELU) v = fmaxf(v, 0.f);
            size_t idx = (size_t)(base + quad * 4 + r) * DHID + ft * 16 + col;
            if (OUT_BF16) outb[idx] = bf16_rne(v);
            else          outf[idx] = v;
        }
    }
}

// ---------------- metadata outputs ----------------

__global__ __launch_bounds__(256) void meta_kernel(const int* __restrict__ tok,
                                                   float* __restrict__ out) {
    int i = blockIdx.x * 256 + threadIdx.x;
    const size_t L0 = (size_t)N_NODES * DHID;
    out[L0 + i]               = (float)tok[i];
    out[L0 + N_NODES + i]     = 1.0f;
    out[L0 + 2 * N_NODES + i] = (float)(i & 2047);
}

// ---------------- launch ----------------

extern "C" void kernel_launch(void* const* d_in, const int* in_sizes, int n_in,
                              void* d_out, int out_size, void* d_ws, size_t ws_size,
                              hipStream_t stream) {
    const int*   tok  = (const int*)d_in[0];
    const int*   esrc = (const int*)d_in[1];
    const int*   edst = esrc + N_EDGES;
    const float* emb  = (const float*)d_in[2];
    const float* Wn   = (const float*)d_in[3];
    const float* bn   = (const float*)d_in[4];
    const float* W1   = (const float*)d_in[5];
    const float* b1   = (const float*)d_in[6];
    const float* W2   = (const float*)d_in[7];
    const float* b2   = (const float*)d_in[8];
    float* out = (float*)d_out;

    char* ws = (char*)d_ws;
    int*   counts  = (int*)(ws);                              // 512 KB @0
    int*   offsets = (int*)(ws + (1u << 19));                 // 512 KB
    int*   cursor  = (int*)(ws + (2u << 19));                 // 512 KB
    float* dinv    = (float*)(ws + (3u << 19));               // 512 KB
    int*   bsums   = (int*)(ws + (4u << 19));                 // 2 KB
    int*   csr     = (int*)(ws + 3 * (1u << 20));             // 2 MB @3MB
    short* Wnb     = (short*)(ws + 5 * (1u << 20));           // 64 KB @5MB
    short* W1b     = (short*)(ws + 5 * (1u << 20) + (1u << 18)); // 32 KB
    short* W2b     = (short*)(ws + 5 * (1u << 20) + (2u << 18)); // 32 KB
    short* embb    = (short*)(ws + 6 * (1u << 20));           // 16.4 MB @6MB
    short* x2b     = (short*)(ws + 24 * (1u << 20));          // 33.5 MB @24MB (ends ~58MB)
    short* xb      = (short*)d_out;                           // 33.5 MB scratch in d_out

    hipMemsetAsync(counts, 0, N_NODES * sizeof(int), stream);
    count_edges<<<N_EDGES / 256, 256, 0, stream>>>(edst, counts);
    scan1<<<N_NODES / 256, 256, 0, stream>>>(counts, offsets, bsums);
    scan2<<<1, 512, 0, stream>>>(bsums);
    scan3<<<N_NODES / 256, 256, 0, stream>>>(counts, offsets, cursor, dinv, bsums);
    fill_csr<<<N_EDGES / 256, 256, 0, stream>>>(esrc, edst, cursor, csr);
    convert_weights<<<65536 / 256, 256, 0, stream>>>(Wn, W1, W2, Wnb, W1b, W2b);
    convert_emb<<<(32000 * 256 / 8) / 256, 256, 0, stream>>>(emb, embb);

    // x = bf16(embb[tok] @ Wn^T + bn) -> xb (d_out scratch)
    gemm_embed<<<N_NODES / 128, 256, 0, stream>>>(embb, tok, Wnb, bn, xb);
    // conv1: fused aggregate+GEMM, relu, bf16 out -> x2b
    fused_conv<true, true><<<N_NODES / 64, 256, 0, stream>>>(
        xb, csr, offsets, counts, dinv, W1b, b1, x2b);
    // conv2: fused, fp32 out straight to d_out (overwrites xb scratch; reads only x2b)
    fused_conv<false, false><<<N_NODES / 64, 256, 0, stream>>>(
        x2b, csr, offsets, counts, dinv, W2b, b2, out);

    meta_kernel<<<N_NODES / 256, 256, 0, stream>>>(tok, out);
}